// Round 16
// baseline (340.646 us; speedup 1.0000x reference)
//
#include <hip/hip_runtime.h>

typedef unsigned short u16;
typedef unsigned int u32;
typedef __attribute__((ext_vector_type(8))) short bfrag;   // 8 x bf16
typedef __attribute__((ext_vector_type(4))) float f32x4;

#define SROW 1032   // padded LDS row stride (bf16 elems): 2064 B
#define ACCW 36     // sh_acc row stride in f32

__device__ __forceinline__ u16 f2bf(float x) {
    unsigned int v = __float_as_uint(x);
    return (u16)((v + 0x7FFFu + ((v >> 16) & 1u)) >> 16);   // RNE
}

// tanh(x) = 1 - 2/(e^{2x}+1): inf-safe.
__device__ __forceinline__ float fast_tanh(float x) {
    float e = __builtin_amdgcn_exp2f(x * 2.885390081777927f);
    return __builtin_fmaf(-2.0f, __builtin_amdgcn_rcpf(e + 1.0f), 1.0f);
}

// ---------------- prologue: bf16 conversions + 32x32 diag-block transpose (f32) ----------------
// diagT[b][i][j] = Bs[32b+j, 32b+i] for j>i else 0  (weight from unit i to unit j)
__global__ void ren_prologue(const float* __restrict__ Bs, const float* __restrict__ Bw,
                             const float* __restrict__ Ds, const float* __restrict__ Dw,
                             u16* __restrict__ bs16, u16* __restrict__ bw16,
                             u16* __restrict__ ds16, u16* __restrict__ dw16,
                             float* __restrict__ diagT)
{
    const int g = blockIdx.x * 256 + threadIdx.x;
    if (g < 262144) {
        const int idx = g * 4;
        const int i = idx >> 10, j = idx & 1023;
        const float4 v = *reinterpret_cast<const float4*>(Bs + idx);
        u16 o[4];
        o[0] = (j + 0 < i) ? f2bf(v.x) : (u16)0;
        o[1] = (j + 1 < i) ? f2bf(v.y) : (u16)0;
        o[2] = (j + 2 < i) ? f2bf(v.z) : (u16)0;
        o[3] = (j + 3 < i) ? f2bf(v.w) : (u16)0;
        *reinterpret_cast<uint2*>(bs16 + idx) = *reinterpret_cast<const uint2*>(o);
    } else if (g < 294912) {
        const int idx = (g - 262144) * 4;
        const float4 v = *reinterpret_cast<const float4*>(Bw + idx);
        u16 o[4] = { f2bf(v.x), f2bf(v.y), f2bf(v.z), f2bf(v.w) };
        *reinterpret_cast<uint2*>(bw16 + idx) = *reinterpret_cast<const uint2*>(o);
    } else if (g < 327680) {
        const int idx = (g - 294912) * 4;
        const float4 v = *reinterpret_cast<const float4*>(Ds + idx);
        u16 o[4] = { f2bf(v.x), f2bf(v.y), f2bf(v.z), f2bf(v.w) };
        *reinterpret_cast<uint2*>(ds16 + idx) = *reinterpret_cast<const uint2*>(o);
    } else if (g < 331776) {
        const int idx = (g - 327680) * 4;
        const float4 v = *reinterpret_cast<const float4*>(Dw + idx);
        u16 o[4] = { f2bf(v.x), f2bf(v.y), f2bf(v.z), f2bf(v.w) };
        *reinterpret_cast<uint2*>(dw16 + idx) = *reinterpret_cast<const uint2*>(o);
    } else if (g < 339968) {
        const int lin0 = (g - 331776) * 4;
        #pragma unroll
        for (int t = 0; t < 4; ++t) {
            const int l = lin0 + t;
            const int bb = l >> 10, rem = l & 1023, i = rem >> 5, j = rem & 31;
            diagT[l] = (j > i) ? Bs[(size_t)(bb * 32 + j) * 1024 + (bb * 32 + i)] : 0.0f;
        }
    }
}

// ---------------- main: barrier-free per-wave recurrence, hierarchical serial ----------------
// 512 wgs x 64 threads (ONE wave), 16 batch rows/wg, 2 wgs/CU. No __syncthreads
// in the main loop. Serial = 8-wide sub-blocks: grouped global weight loads
// (wave-uniform, L2-broadcast; one wait per group), short tanh chains, off-chain
// panel updates. GEMM partial for b+1 issued BEFORE serial(b) so its loads fly
// underneath; finished with the fresh s_b afterwards (same-wave LDS ordering).
__global__ __launch_bounds__(64, 1) void ren_main(
    const float* __restrict__ u,
    const u16* __restrict__ bs16, const u16* __restrict__ bw16,
    const u16* __restrict__ ds16, const u16* __restrict__ dw16,
    const float* __restrict__ diagT,
    float* __restrict__ out)
{
    __shared__ __align__(16) u16   sh_S[16 * SROW];     // s history bf16 [16][1024+pad]
    __shared__ __align__(16) float sh_acc[16 * ACCW];   // transpose tile [16][36]

    const int lane = threadIdx.x;
    const int lr   = lane & 15;
    const int lk8  = (lane >> 4) << 3;
    const int row0 = blockIdx.x << 4;      // 16 batch rows per wg

    // u A-fragments for the 16 rows (k = 0..127)
    bfrag fu[4];
    {
        const float* up = u + (size_t)(row0 + lr) * 128 + lk8;
        #pragma unroll
        for (int kk = 0; kk < 4; ++kk) {
            float4 a = *reinterpret_cast<const float4*>(up + kk * 32);
            float4 c = *reinterpret_cast<const float4*>(up + kk * 32 + 4);
            bfrag f;
            f[0] = (short)f2bf(a.x); f[1] = (short)f2bf(a.y);
            f[2] = (short)f2bf(a.z); f[3] = (short)f2bf(a.w);
            f[4] = (short)f2bf(c.x); f[5] = (short)f2bf(c.y);
            f[6] = (short)f2bf(c.z); f[7] = (short)f2bf(c.w);
            fu[kk] = f;
        }
    }

    f32x4 acc0, acc1;

    // ---- bootstrap: acc(0) = Bu(0) -> sh_acc ----
    {
        acc0 = (f32x4){0.f,0.f,0.f,0.f}; acc1 = (f32x4){0.f,0.f,0.f,0.f};
        const u16* p0 = bw16 + (size_t)lr * 128 + lk8;
        const u16* p1 = bw16 + (size_t)(16 + lr) * 128 + lk8;
        #pragma unroll
        for (int kk = 0; kk < 4; ++kk) {
            acc0 = __builtin_amdgcn_mfma_f32_16x16x32_bf16(fu[kk], *reinterpret_cast<const bfrag*>(p0 + kk * 32), acc0, 0, 0, 0);
            acc1 = __builtin_amdgcn_mfma_f32_16x16x32_bf16(fu[kk], *reinterpret_cast<const bfrag*>(p1 + kk * 32), acc1, 0, 0, 0);
        }
        const int m = (lane >> 4) << 2;
        #pragma unroll
        for (int rr = 0; rr < 4; ++rr) {
            sh_acc[(m + rr) * ACCW + lr]      = acc0[rr];
            sh_acc[(m + rr) * ACCW + 16 + lr] = acc1[rr];
        }
    }

    for (int b = 0; b < 32; ++b) {
        const int nb = b + 1;
        bfrag bfin0, bfin1;

        // ---------- GEMM partial for block b+1 (kc < b) — loads fly under serial ----------
        if (nb < 32) {
            const u16* bsp0 = bs16 + (size_t)((nb << 5) + lr) * 1024 + lk8;
            const u16* bsp1 = bs16 + (size_t)((nb << 5) + 16 + lr) * 1024 + lk8;
            bfin0 = *reinterpret_cast<const bfrag*>(bsp0 + (b << 5));   // finish k-slice
            bfin1 = *reinterpret_cast<const bfrag*>(bsp1 + (b << 5));

            acc0 = (f32x4){0.f,0.f,0.f,0.f}; acc1 = (f32x4){0.f,0.f,0.f,0.f};
            const u16* q0 = bw16 + (size_t)((nb << 5) + lr) * 128 + lk8;
            const u16* q1 = bw16 + (size_t)((nb << 5) + 16 + lr) * 128 + lk8;
            #pragma unroll
            for (int kk = 0; kk < 4; ++kk) {
                acc0 = __builtin_amdgcn_mfma_f32_16x16x32_bf16(fu[kk], *reinterpret_cast<const bfrag*>(q0 + kk * 32), acc0, 0, 0, 0);
                acc1 = __builtin_amdgcn_mfma_f32_16x16x32_bf16(fu[kk], *reinterpret_cast<const bfrag*>(q1 + kk * 32), acc1, 0, 0, 0);
            }
            const u16* ssp = sh_S + lr * SROW + lk8;
            #pragma unroll 8
            for (int kc = 0; kc < b; ++kc) {
                bfrag af = *reinterpret_cast<const bfrag*>(ssp + (kc << 5));
                acc0 = __builtin_amdgcn_mfma_f32_16x16x32_bf16(af, *reinterpret_cast<const bfrag*>(bsp0 + (kc << 5)), acc0, 0, 0, 0);
                acc1 = __builtin_amdgcn_mfma_f32_16x16x32_bf16(af, *reinterpret_cast<const bfrag*>(bsp1 + (kc << 5)), acc1, 0, 0, 0);
            }
        }

        // ---------- serial: hierarchical solve of block b (lanes 0-15 = rows) ----------
        if (lane < 16) {
            float part[32];
            const float* accr = sh_acc + lane * ACCW;
            #pragma unroll
            for (int q = 0; q < 8; ++q) {
                float4 v = reinterpret_cast<const float4*>(accr)[q];
                part[4*q+0] = v.x; part[4*q+1] = v.y; part[4*q+2] = v.z; part[4*q+3] = v.w;
            }
            const float* gb = diagT + (b << 10);   // wave-uniform -> L2 broadcast
            u16* srow = sh_S + lane * SROW + (b << 5);

            #pragma unroll
            for (int g = 0; g < 4; ++g) {
                // (a) diagonal 8x8: 16 quads as one grouped load burst
                float4 dq0[8], dq1[8];
                #pragma unroll
                for (int i = 0; i < 8; ++i) {
                    dq0[i] = *reinterpret_cast<const float4*>(gb + (8*g + i) * 32 + 8*g);
                    dq1[i] = *reinterpret_cast<const float4*>(gb + (8*g + i) * 32 + 8*g + 4);
                }
                float s8[8];
                #pragma unroll
                for (int i = 0; i < 8; ++i) {
                    float s = fast_tanh(part[8*g + i]);
                    s8[i] = s;
                    part[8*g+0] = __builtin_fmaf(dq0[i].x, s, part[8*g+0]);
                    part[8*g+1] = __builtin_fmaf(dq0[i].y, s, part[8*g+1]);
                    part[8*g+2] = __builtin_fmaf(dq0[i].z, s, part[8*g+2]);
                    part[8*g+3] = __builtin_fmaf(dq0[i].w, s, part[8*g+3]);
                    part[8*g+4] = __builtin_fmaf(dq1[i].x, s, part[8*g+4]);
                    part[8*g+5] = __builtin_fmaf(dq1[i].y, s, part[8*g+5]);
                    part[8*g+6] = __builtin_fmaf(dq1[i].z, s, part[8*g+6]);
                    part[8*g+7] = __builtin_fmaf(dq1[i].w, s, part[8*g+7]);
                }
                {   // pack the 8 fresh s values -> sh_S (one 16B store)
                    uint4 pk;
                    u32 r0 = (__float_as_uint(s8[0]) + 0x8000u) >> 16;
                    u32 r1 = (__float_as_uint(s8[1]) + 0x8000u) >> 16;
                    u32 r2 = (__float_as_uint(s8[2]) + 0x8000u) >> 16;
                    u32 r3 = (__float_as_uint(s8[3]) + 0x8000u) >> 16;
                    u32 r4 = (__float_as_uint(s8[4]) + 0x8000u) >> 16;
                    u32 r5 = (__float_as_uint(s8[5]) + 0x8000u) >> 16;
                    u32 r6 = (__float_as_uint(s8[6]) + 0x8000u) >> 16;
                    u32 r7 = (__float_as_uint(s8[7]) + 0x8000u) >> 16;
                    pk.x = r0 | (r1 << 16);
                    pk.y = r2 | (r3 << 16);
                    pk.z = r4 | (r5 << 16);
                    pk.w = r6 | (r7 << 16);
                    *reinterpret_cast<uint4*>(srow + 8 * g) = pk;
                }
                // (b) panel: units 8g+8..31 += W * s8 — off-chain, 2-row chunks
                #pragma unroll
                for (int h = 0; h < 4; ++h) {
                    float4 pw[2][8];
                    #pragma unroll
                    for (int r = 0; r < 2; ++r)
                        #pragma unroll
                        for (int q = 2*g + 2; q < 8; ++q)
                            pw[r][q] = *reinterpret_cast<const float4*>(gb + (8*g + 2*h + r) * 32 + 4*q);
                    #pragma unroll
                    for (int r = 0; r < 2; ++r) {
                        float s = s8[2*h + r];
                        #pragma unroll
                        for (int q = 2*g + 2; q < 8; ++q) {
                            float4 w = pw[r][q];
                            part[4*q+0] = __builtin_fmaf(w.x, s, part[4*q+0]);
                            part[4*q+1] = __builtin_fmaf(w.y, s, part[4*q+1]);
                            part[4*q+2] = __builtin_fmaf(w.z, s, part[4*q+2]);
                            part[4*q+3] = __builtin_fmaf(w.w, s, part[4*q+3]);
                        }
                    }
                }
            }
        }

        // ---------- finish block b+1 with the fresh s_b k-slice -> sh_acc ----------
        if (nb < 32) {
            const u16* ssp = sh_S + lr * SROW + lk8;
            bfrag af = *reinterpret_cast<const bfrag*>(ssp + (b << 5));
            acc0 = __builtin_amdgcn_mfma_f32_16x16x32_bf16(af, bfin0, acc0, 0, 0, 0);
            acc1 = __builtin_amdgcn_mfma_f32_16x16x32_bf16(af, bfin1, acc1, 0, 0, 0);
            const int m = (lane >> 4) << 2;
            #pragma unroll
            for (int rr = 0; rr < 4; ++rr) {
                sh_acc[(m + rr) * ACCW + lr]      = acc0[rr];
                sh_acc[(m + rr) * ACCW + 16 + lr] = acc1[rr];
            }
        }
    }

    // ---------------- epilogue: y = s @ Ds^T + u @ D^T  (16 x 128 per wg) ----------------
    f32x4 ey[8];
    #pragma unroll
    for (int t = 0; t < 8; ++t) ey[t] = (f32x4){0.f,0.f,0.f,0.f};

    const u16* ssp = sh_S + lr * SROW + lk8;
    #pragma unroll 2
    for (int kc = 0; kc < 32; ++kc) {
        bfrag af = *reinterpret_cast<const bfrag*>(ssp + (kc << 5));
        #pragma unroll
        for (int t = 0; t < 8; ++t) {
            bfrag bf = *reinterpret_cast<const bfrag*>(ds16 + (size_t)(t * 16 + lr) * 1024 + (kc << 5) + lk8);
            ey[t] = __builtin_amdgcn_mfma_f32_16x16x32_bf16(af, bf, ey[t], 0, 0, 0);
        }
    }
    #pragma unroll
    for (int kk = 0; kk < 4; ++kk) {
        #pragma unroll
        for (int t = 0; t < 8; ++t) {
            bfrag bf = *reinterpret_cast<const bfrag*>(dw16 + (t * 16 + lr) * 128 + (kk << 5) + lk8);
            ey[t] = __builtin_amdgcn_mfma_f32_16x16x32_bf16(fu[kk], bf, ey[t], 0, 0, 0);
        }
    }
    {
        const int mbase = row0 + ((lane >> 4) << 2);
        #pragma unroll
        for (int t = 0; t < 8; ++t) {
            #pragma unroll
            for (int rr = 0; rr < 4; ++rr)
                out[(size_t)(mbase + rr) * 128 + t * 16 + lr] = ey[t][rr];
        }
    }
}

extern "C" void kernel_launch(void* const* d_in, const int* in_sizes, int n_in,
                              void* d_out, int out_size, void* d_ws, size_t ws_size,
                              hipStream_t stream)
{
    const float* u  = (const float*)d_in[0];   // [8192,128]
    const float* Bw = (const float*)d_in[1];   // [1024,128]
    const float* Bs = (const float*)d_in[2];   // [1024,1024]
    const float* Ds = (const float*)d_in[3];   // [128,1024]
    const float* Dw = (const float*)d_in[4];   // [128,128]
    float* out = (float*)d_out;

    u16* bs16 = (u16*)d_ws;                    // 1024*1024 bf16
    u16* bw16 = bs16 + 1024 * 1024;            // 1024*128
    u16* ds16 = bw16 + 1024 * 128;             // 128*1024
    u16* dw16 = ds16 + 128 * 1024;             // 128*128
    float* diagT = (float*)(dw16 + 128 * 128); // 32 blocks x 32x32 f32, transposed

    ren_prologue<<<1328, 256, 0, stream>>>(Bs, Bw, Ds, Dw, bs16, bw16, ds16, dw16, diagT);
    ren_main<<<512, 64, 0, stream>>>(u, bs16, bw16, ds16, dw16, diagT, out);
}

// Round 17
// 165.519 us; speedup vs baseline: 2.0580x; 2.0580x over previous
//
#include <hip/hip_runtime.h>

typedef unsigned short u16;
typedef unsigned int u32;
typedef __attribute__((ext_vector_type(8))) short bfrag;   // 8 x bf16
typedef __attribute__((ext_vector_type(4))) float f32x4;

#define SROW 1032   // padded LDS row stride (bf16 elems): 2064 B
#define ACCW 36     // sh_acc row stride in f32

__device__ __forceinline__ u16 f2bf(float x) {
    unsigned int v = __float_as_uint(x);
    return (u16)((v + 0x7FFFu + ((v >> 16) & 1u)) >> 16);   // RNE
}

// tanh(x) = 1 - 2/(e^{2x}+1): inf-safe.
__device__ __forceinline__ float fast_tanh(float x) {
    float e = __builtin_amdgcn_exp2f(x * 2.885390081777927f);
    return __builtin_fmaf(-2.0f, __builtin_amdgcn_rcpf(e + 1.0f), 1.0f);
}

// ---------------- prologue: bf16 conversions + 32x32 diag-block transpose (f32) ----------------
// diagT[b][i][j] = Bs[32b+j, 32b+i] for j>i else 0  (weight from unit i to unit j)
__global__ void ren_prologue(const float* __restrict__ Bs, const float* __restrict__ Bw,
                             const float* __restrict__ Ds, const float* __restrict__ Dw,
                             u16* __restrict__ bs16, u16* __restrict__ bw16,
                             u16* __restrict__ ds16, u16* __restrict__ dw16,
                             float* __restrict__ diagT)
{
    const int g = blockIdx.x * 256 + threadIdx.x;
    if (g < 262144) {
        const int idx = g * 4;
        const int i = idx >> 10, j = idx & 1023;
        const float4 v = *reinterpret_cast<const float4*>(Bs + idx);
        u16 o[4];
        o[0] = (j + 0 < i) ? f2bf(v.x) : (u16)0;
        o[1] = (j + 1 < i) ? f2bf(v.y) : (u16)0;
        o[2] = (j + 2 < i) ? f2bf(v.z) : (u16)0;
        o[3] = (j + 3 < i) ? f2bf(v.w) : (u16)0;
        *reinterpret_cast<uint2*>(bs16 + idx) = *reinterpret_cast<const uint2*>(o);
    } else if (g < 294912) {
        const int idx = (g - 262144) * 4;
        const float4 v = *reinterpret_cast<const float4*>(Bw + idx);
        u16 o[4] = { f2bf(v.x), f2bf(v.y), f2bf(v.z), f2bf(v.w) };
        *reinterpret_cast<uint2*>(bw16 + idx) = *reinterpret_cast<const uint2*>(o);
    } else if (g < 327680) {
        const int idx = (g - 294912) * 4;
        const float4 v = *reinterpret_cast<const float4*>(Ds + idx);
        u16 o[4] = { f2bf(v.x), f2bf(v.y), f2bf(v.z), f2bf(v.w) };
        *reinterpret_cast<uint2*>(ds16 + idx) = *reinterpret_cast<const uint2*>(o);
    } else if (g < 331776) {
        const int idx = (g - 327680) * 4;
        const float4 v = *reinterpret_cast<const float4*>(Dw + idx);
        u16 o[4] = { f2bf(v.x), f2bf(v.y), f2bf(v.z), f2bf(v.w) };
        *reinterpret_cast<uint2*>(dw16 + idx) = *reinterpret_cast<const uint2*>(o);
    } else if (g < 339968) {
        const int lin0 = (g - 331776) * 4;
        #pragma unroll
        for (int t = 0; t < 4; ++t) {
            const int l = lin0 + t;
            const int bb = l >> 10, rem = l & 1023, i = rem >> 5, j = rem & 31;
            diagT[l] = (j > i) ? Bs[(size_t)(bb * 32 + j) * 1024 + (bb * 32 + i)] : 0.0f;
        }
    }
}

// ---------------- main: producer/consumer, hierarchical serial, 2 wgs/CU ----------------
// 512 wgs x 192 threads, 16 batch rows/wg -> 2 wgs co-resident per CU so one
// wg's barrier/latency stalls are filled by the other's work.
// Waves 0,1: GEMM producers (nt = wave). Wave 2: serial consumer (lanes 0-15 =
// batch rows), hierarchical 8-wide sub-blocks reading weights from LDS sh_dT.
__global__ __launch_bounds__(192, 1) void ren_main(
    const float* __restrict__ u,
    const u16* __restrict__ bs16, const u16* __restrict__ bw16,
    const u16* __restrict__ ds16, const u16* __restrict__ dw16,
    const float* __restrict__ diagT,
    float* __restrict__ out)
{
    __shared__ __align__(16) u16   sh_S[16 * SROW];    // s history bf16 [16][1024+pad]
    __shared__ __align__(16) float sh_acc[16 * ACCW];  // pre-activation tile [16][36]
    __shared__ __align__(16) float sh_dT[2][1024];     // dbuf diag block f32 [32][32]

    const int tid  = threadIdx.x;
    const int wave = tid >> 6;
    const int lane = tid & 63;
    const int nt   = wave & 1;             // col-tile for GEMM waves
    const int lr   = lane & 15;
    const int lk8  = (lane >> 4) << 3;
    const int row0 = blockIdx.x << 4;      // 16 batch rows per wg

    bfrag fu[4];                           // u A-frags (GEMM waves only)
    f32x4 acc;                             // next-block partial accumulator

    if (wave < 2) {
        const float* up = u + (size_t)(row0 + lr) * 128 + lk8;
        #pragma unroll
        for (int kk = 0; kk < 4; ++kk) {
            float4 a = *reinterpret_cast<const float4*>(up + kk * 32);
            float4 c = *reinterpret_cast<const float4*>(up + kk * 32 + 4);
            bfrag f;
            f[0] = (short)f2bf(a.x); f[1] = (short)f2bf(a.y);
            f[2] = (short)f2bf(a.z); f[3] = (short)f2bf(a.w);
            f[4] = (short)f2bf(c.x); f[5] = (short)f2bf(c.y);
            f[6] = (short)f2bf(c.z); f[7] = (short)f2bf(c.w);
            fu[kk] = f;
        }
        // stage dT block 0 (1024 f32 by threads 0-127)
        {
            const float4* g = reinterpret_cast<const float4*>(diagT);
            float4 a = g[2 * tid], c = g[2 * tid + 1];
            *reinterpret_cast<float4*>(&sh_dT[0][tid * 8])     = a;
            *reinterpret_cast<float4*>(&sh_dT[0][tid * 8 + 4]) = c;
        }
        // block 0 pre-activations = Bu only (each wave: 16 rows x 16 cols)
        acc = (f32x4){0.f, 0.f, 0.f, 0.f};
        const u16* p0 = bw16 + (size_t)((nt << 4) + lr) * 128 + lk8;
        #pragma unroll
        for (int kk = 0; kk < 4; ++kk)
            acc = __builtin_amdgcn_mfma_f32_16x16x32_bf16(fu[kk], *reinterpret_cast<const bfrag*>(p0 + kk * 32), acc, 0, 0, 0);
        const int m = (lane >> 4) << 2;
        #pragma unroll
        for (int rr = 0; rr < 4; ++rr)
            sh_acc[(m + rr) * ACCW + (nt << 4) + lr] = acc[rr];
    }
    __syncthreads();

    for (int b = 0; b < 32; ++b) {
        bfrag bfin;                        // finish B-frag, preloaded pre-barrier
        const int nb = b + 1;

        if (wave == 2) {
            // ---------- serial consumer: hierarchical solve of block b ----------
            if (lane < 16) {
                float part[32];
                const float* accr = sh_acc + lane * ACCW;
                #pragma unroll
                for (int q = 0; q < 8; ++q) {
                    float4 v = reinterpret_cast<const float4*>(accr)[q];
                    part[4*q+0] = v.x; part[4*q+1] = v.y; part[4*q+2] = v.z; part[4*q+3] = v.w;
                }
                const float4* dT4 = reinterpret_cast<const float4*>(&sh_dT[b & 1][0]);
                u16* srow = sh_S + lane * SROW + (b << 5);

                #pragma unroll
                for (int g = 0; g < 4; ++g) {
                    // (a) diagonal 8x8: preload 16 quads as one independent group
                    float4 dq0[8], dq1[8];
                    #pragma unroll
                    for (int i = 0; i < 8; ++i) {
                        dq0[i] = dT4[(8 * g + i) * 8 + 2 * g];
                        dq1[i] = dT4[(8 * g + i) * 8 + 2 * g + 1];
                    }
                    float s8[8];
                    #pragma unroll
                    for (int i = 0; i < 8; ++i) {
                        float s = fast_tanh(part[8 * g + i]);
                        s8[i] = s;
                        part[8*g+0] = __builtin_fmaf(dq0[i].x, s, part[8*g+0]);
                        part[8*g+1] = __builtin_fmaf(dq0[i].y, s, part[8*g+1]);
                        part[8*g+2] = __builtin_fmaf(dq0[i].z, s, part[8*g+2]);
                        part[8*g+3] = __builtin_fmaf(dq0[i].w, s, part[8*g+3]);
                        part[8*g+4] = __builtin_fmaf(dq1[i].x, s, part[8*g+4]);
                        part[8*g+5] = __builtin_fmaf(dq1[i].y, s, part[8*g+5]);
                        part[8*g+6] = __builtin_fmaf(dq1[i].z, s, part[8*g+6]);
                        part[8*g+7] = __builtin_fmaf(dq1[i].w, s, part[8*g+7]);
                    }
                    {   // pack the 8 fresh s values -> sh_S (one 16B store)
                        uint4 pk;
                        u32 r0 = (__float_as_uint(s8[0]) + 0x8000u) >> 16;
                        u32 r1 = (__float_as_uint(s8[1]) + 0x8000u) >> 16;
                        u32 r2 = (__float_as_uint(s8[2]) + 0x8000u) >> 16;
                        u32 r3 = (__float_as_uint(s8[3]) + 0x8000u) >> 16;
                        u32 r4 = (__float_as_uint(s8[4]) + 0x8000u) >> 16;
                        u32 r5 = (__float_as_uint(s8[5]) + 0x8000u) >> 16;
                        u32 r6 = (__float_as_uint(s8[6]) + 0x8000u) >> 16;
                        u32 r7 = (__float_as_uint(s8[7]) + 0x8000u) >> 16;
                        pk.x = r0 | (r1 << 16);
                        pk.y = r2 | (r3 << 16);
                        pk.z = r4 | (r5 << 16);
                        pk.w = r6 | (r7 << 16);
                        *reinterpret_cast<uint4*>(srow + 8 * g) = pk;
                    }
                    // (b) panel: units 8g+8..31 += W * s8 — off-chain, 4-row chunks
                    #pragma unroll
                    for (int h = 0; h < 2; ++h) {
                        float4 pw[4][8];
                        #pragma unroll
                        for (int i = 0; i < 4; ++i)
                            #pragma unroll
                            for (int q = 2 * g + 2; q < 8; ++q)
                                pw[i][q] = dT4[(8 * g + 4 * h + i) * 8 + q];
                        #pragma unroll
                        for (int i = 0; i < 4; ++i) {
                            float s = s8[4 * h + i];
                            #pragma unroll
                            for (int q = 2 * g + 2; q < 8; ++q) {
                                float4 w = pw[i][q];
                                part[4*q+0] = __builtin_fmaf(w.x, s, part[4*q+0]);
                                part[4*q+1] = __builtin_fmaf(w.y, s, part[4*q+1]);
                                part[4*q+2] = __builtin_fmaf(w.z, s, part[4*q+2]);
                                part[4*q+3] = __builtin_fmaf(w.w, s, part[4*q+3]);
                            }
                        }
                    }
                }
            }
        } else if (b < 31) {
            // ---------- GEMM producers: partial for block b+1 (kc < b) ----------
            float4 st0, st1;
            {   // stage dT[b+1] (loads early, LDS writes after the GEMM)
                const float4* g = reinterpret_cast<const float4*>(diagT + (nb << 10));
                st0 = g[2 * tid]; st1 = g[2 * tid + 1];
            }
            const int ng = (nb << 5) + (nt << 4) + lr;     // global hid unit
            bfin = *reinterpret_cast<const bfrag*>(bs16 + (size_t)ng * 1024 + (b << 5) + lk8);

            acc = (f32x4){0.f, 0.f, 0.f, 0.f};
            const u16* p0 = bw16 + (size_t)ng * 128 + lk8;
            #pragma unroll
            for (int kk = 0; kk < 4; ++kk)
                acc = __builtin_amdgcn_mfma_f32_16x16x32_bf16(fu[kk], *reinterpret_cast<const bfrag*>(p0 + kk * 32), acc, 0, 0, 0);

            const u16* bsp = bs16 + (size_t)ng * 1024 + lk8;
            const u16* ssp = sh_S + lr * SROW + lk8;
            #pragma unroll 8
            for (int kc = 0; kc < b; ++kc) {
                bfrag af = *reinterpret_cast<const bfrag*>(ssp + (kc << 5));
                acc = __builtin_amdgcn_mfma_f32_16x16x32_bf16(af, *reinterpret_cast<const bfrag*>(bsp + (kc << 5)), acc, 0, 0, 0);
            }
            *reinterpret_cast<float4*>(&sh_dT[nb & 1][tid * 8])     = st0;
            *reinterpret_cast<float4*>(&sh_dT[nb & 1][tid * 8 + 4]) = st1;
        }
        __syncthreads();   // s_b visible; partials done

        if (wave < 2 && b < 31) {
            // ---------- finish block b+1 with the fresh s_b k-slice ----------
            const u16* ssp = sh_S + lr * SROW + lk8;
            bfrag af = *reinterpret_cast<const bfrag*>(ssp + (b << 5));
            acc = __builtin_amdgcn_mfma_f32_16x16x32_bf16(af, bfin, acc, 0, 0, 0);
            const int m = (lane >> 4) << 2;
            #pragma unroll
            for (int rr = 0; rr < 4; ++rr)
                sh_acc[(m + rr) * ACCW + (nt << 4) + lr] = acc[rr];
        }
        __syncthreads();   // sh_acc ready for serial(b+1)
    }

    if (wave >= 2) return;

    // ---------------- epilogue: y = s @ Ds^T + u @ D^T  (16 x 128 per wg) ----------------
    f32x4 ey[4];
    #pragma unroll
    for (int t = 0; t < 4; ++t) ey[t] = (f32x4){0.f, 0.f, 0.f, 0.f};

    const u16* ssp = sh_S + lr * SROW + lk8;
    #pragma unroll 4
    for (int kc = 0; kc < 32; ++kc) {
        bfrag af = *reinterpret_cast<const bfrag*>(ssp + (kc << 5));
        #pragma unroll
        for (int t = 0; t < 4; ++t) {
            const int n = ((nt << 2) + t) * 16 + lr;
            bfrag bf = *reinterpret_cast<const bfrag*>(ds16 + (size_t)n * 1024 + (kc << 5) + lk8);
            ey[t] = __builtin_amdgcn_mfma_f32_16x16x32_bf16(af, bf, ey[t], 0, 0, 0);
        }
    }
    #pragma unroll
    for (int kk = 0; kk < 4; ++kk) {
        #pragma unroll
        for (int t = 0; t < 4; ++t) {
            const int n = ((nt << 2) + t) * 16 + lr;
            bfrag bf = *reinterpret_cast<const bfrag*>(dw16 + n * 128 + (kk << 5) + lk8);
            ey[t] = __builtin_amdgcn_mfma_f32_16x16x32_bf16(fu[kk], bf, ey[t], 0, 0, 0);
        }
    }
    {
        const int mbase = row0 + ((lane >> 4) << 2);
        #pragma unroll
        for (int t = 0; t < 4; ++t) {
            const int n = ((nt << 2) + t) * 16 + lr;
            #pragma unroll
            for (int rr = 0; rr < 4; ++rr)
                out[(size_t)(mbase + rr) * 128 + n] = ey[t][rr];
        }
    }
}

extern "C" void kernel_launch(void* const* d_in, const int* in_sizes, int n_in,
                              void* d_out, int out_size, void* d_ws, size_t ws_size,
                              hipStream_t stream)
{
    const float* u  = (const float*)d_in[0];   // [8192,128]
    const float* Bw = (const float*)d_in[1];   // [1024,128]
    const float* Bs = (const float*)d_in[2];   // [1024,1024]
    const float* Ds = (const float*)d_in[3];   // [128,1024]
    const float* Dw = (const float*)d_in[4];   // [128,128]
    float* out = (float*)d_out;

    u16* bs16 = (u16*)d_ws;                    // 1024*1024 bf16
    u16* bw16 = bs16 + 1024 * 1024;            // 1024*128
    u16* ds16 = bw16 + 1024 * 128;             // 128*1024
    u16* dw16 = ds16 + 128 * 1024;             // 128*128
    float* diagT = (float*)(dw16 + 128 * 128); // 32 blocks x 32x32 f32, transposed

    ren_prologue<<<1328, 256, 0, stream>>>(Bs, Bw, Ds, Dw, bs16, bw16, ds16, dw16, diagT);
    ren_main<<<512, 192, 0, stream>>>(u, bs16, bw16, ds16, dw16, diagT, out);
}